// Round 1
// baseline (154.241 us; speedup 1.0000x reference)
//
#include <hip/hip_runtime.h>
#include <hip/hip_bf16.h>

#define ROWS 64
#define NBT 4            // ROWS/16
#define THREADS 512

typedef __attribute__((ext_vector_type(4))) float f32x4;
typedef __attribute__((ext_vector_type(8))) short s16x8;

__device__ __forceinline__ unsigned short bfbits(float f) {
  __bf16 h = (__bf16)f;
  return __builtin_bit_cast(unsigned short, h);
}
__device__ __forceinline__ float bf2f(unsigned short h) {
  unsigned u = ((unsigned)h) << 16;
  return __builtin_bit_cast(float, u);
}

// ---------------- prep: pack weights into MFMA A-fragment order (bf16) ----------------
// A-frag for mfma_f32_16x16x32_bf16: lane l holds A[m = l&15][k = (l>>4)*8 + j], j=0..7
// w1f: [c:12][ft:32][lane:64][8]   (K=384 of W1; k=384 handled as rank-1 in epilogue)
// w2f: [c:16][ft:16][lane:64][8]
// w3f: [c: 8][ft:12][lane:64][8]
// whT: [head:128][j:16][f:192] bf16
__global__ void prep_kernel(const float* __restrict__ W1, const float* __restrict__ W2,
                            const float* __restrict__ W3, const float* __restrict__ Wh,
                            unsigned short* __restrict__ w1f, unsigned short* __restrict__ w2f,
                            unsigned short* __restrict__ w3f, unsigned short* __restrict__ whT) {
  int i = blockIdx.x * blockDim.x + threadIdx.x;
  const int S1 = 12*32*64*8, S2 = 16*16*64*8, S3 = 8*12*64*8, S4 = 128*16*192;
  if (i < S1) {
    int j = i & 7, lane = (i >> 3) & 63, ft = (i >> 9) & 31, c = i >> 14;
    int k = c*32 + ((lane >> 4) << 3) + j, f = (ft << 4) + (lane & 15);
    w1f[i] = bfbits(W1[k*512 + f]);
    return;
  }
  i -= S1;
  if (i < S2) {
    int j = i & 7, lane = (i >> 3) & 63, ft = (i >> 9) & 15, c = i >> 13;
    int k = c*32 + ((lane >> 4) << 3) + j, f = (ft << 4) + (lane & 15);
    w2f[i] = bfbits(W2[k*256 + f]);
    return;
  }
  i -= S2;
  if (i < S3) {
    int j = i & 7, lane = (i >> 3) & 63, t = i >> 9;
    int c = t / 12, ft = t - c*12;
    int k = c*32 + ((lane >> 4) << 3) + j, f = (ft << 4) + (lane & 15);
    w3f[i] = bfbits(W3[k*192 + f]);
    return;
  }
  i -= S3;
  if (i < S4) {
    int f = i % 192;
    int t = i / 192;
    int j = t & 15;
    int head = t >> 4;
    whT[i] = bfbits(Wh[f*2048 + head*16 + j]);
  }
}

// ---------------- fused MLP ----------------
// LDS layout (bytes):
//   h1f  @ 0      : 65536  (h1^T as GEMM2 B-frags: [c2:16][bt:4][lane:64][8] bf16)
//   xs   @ 65536  : 16384  (2 x [64 rows][32 k] f32, quad-XOR swizzled)  -- aliased with:
//   h2f  @ 65536  : 32768  ([c3:8][bt:4][lane:64][8] bf16)
//   h3p  @ 98304  : 50176  ([64 rows][196 f] f32, padded stride vs bank conflicts)
//   b1s  @ 148480 : 2048 | b2s @ 150528 : 1024 | b3s @ 151552 : 768
//   w1l  @ 152320 : 2048 (W1[384][:]) | x384 @ 154368 : 256
#define MFMA(a, b, c) __builtin_amdgcn_mfma_f32_16x16x32_bf16((a), (b), (c), 0, 0, 0)

__launch_bounds__(THREADS, 2)
__global__ void fused_mlp(const float* __restrict__ x,
                          const float* __restrict__ W1,
                          const float* __restrict__ b1,
                          const float* __restrict__ b2,
                          const float* __restrict__ b3,
                          const float* __restrict__ bh,
                          const int* __restrict__ qid,
                          const int* __restrict__ corr,
                          const unsigned short* __restrict__ w1f,
                          const unsigned short* __restrict__ w2f,
                          const unsigned short* __restrict__ w3f,
                          const unsigned short* __restrict__ whT,
                          float* __restrict__ out) {
  __shared__ __align__(16) unsigned char lds[154624];
  unsigned short* h1f = (unsigned short*)(lds);
  float* xs           = (float*)(lds + 65536);
  unsigned short* h2f = (unsigned short*)(lds + 65536);
  float* h3p          = (float*)(lds + 98304);
  float* b1s          = (float*)(lds + 148480);
  float* b2s          = (float*)(lds + 150528);
  float* b3s          = (float*)(lds + 151552);
  float* w1l          = (float*)(lds + 152320);
  float* x384         = (float*)(lds + 154368);

  const int tid  = threadIdx.x;
  const int lane = tid & 63;
  const int w    = tid >> 6;     // wave 0..7
  const int b0   = blockIdx.x * ROWS;
  const int l15  = lane & 15;
  const int lh   = lane >> 4;    // 0..3

  // stage small constants
  b1s[tid & 511] = b1[tid & 511];
  w1l[tid & 511] = W1[384*512 + (tid & 511)];
  if (tid < 256) b2s[tid] = b2[tid];
  if (tid < 192) b3s[tid] = b3[tid];
  if (tid < 64)  x384[tid] = x[(b0 + tid)*385 + 384];

  // x chunk staging: chunk c = [64 rows][32 k] f32, 2048 dwords, 4 per thread.
  // dword i -> row b=i>>5, phys-quad qp=(i>>3)&3, e=i&7; logical quad q = qp ^ (b&3)
  auto stageX = [&](int c, int buf) {
    #pragma unroll
    for (int s = 0; s < 4; ++s) {
      int i  = s*512 + tid;
      int bb = i >> 5;
      int qp = (i >> 3) & 3;
      int e  = i & 7;
      int q  = qp ^ (bb & 3);
      const float* g = x + (b0 + bb)*385 + c*32 + q*8 + e;
      float* l = xs + buf*2048 + s*512 + (tid & ~63);   // wave-uniform LDS base
      __builtin_amdgcn_global_load_lds((const __attribute__((address_space(1))) void*)g,
                                       (__attribute__((address_space(3))) void*)l, 4, 0, 0);
    }
  };

  // ---------------- GEMM1: h1^T[512f x 64b] = W1^T x^T, K = 384 (+rank-1 k=384) ----------------
  f32x4 acc1[4][NBT];
  #pragma unroll
  for (int a = 0; a < 4; ++a)
    #pragma unroll
    for (int bt = 0; bt < NBT; ++bt) acc1[a][bt] = (f32x4)0.0f;

  s16x8 afrag[2][4];
  stageX(0, 0);
  #pragma unroll
  for (int a = 0; a < 4; ++a)
    afrag[0][a] = *(const s16x8*)(w1f + ((((0*32) + (w*4 + a))*64 + lane) << 3));

  #pragma unroll
  for (int c = 0; c < 12; ++c) {
    __syncthreads();   // chunk c staged; previous reads done
    if (c + 1 < 12) {
      stageX(c + 1, (c + 1) & 1);
      #pragma unroll
      for (int a = 0; a < 4; ++a)
        afrag[(c+1)&1][a] = *(const s16x8*)(w1f + ((((c+1)*32 + (w*4 + a))*64 + lane) << 3));
    }
    const float* xb = xs + (c & 1)*2048;
    #pragma unroll
    for (int bt = 0; bt < NBT; ++bt) {
      int bb = (bt << 4) + l15;
      int qp = lh ^ (bb & 3);
      const float* p = xb + bb*32 + qp*8;
      f32x4 lo = *(const f32x4*)p;
      f32x4 hi = *(const f32x4*)(p + 4);
      s16x8 bfr;
      bfr[0] = (short)bfbits(lo[0]); bfr[1] = (short)bfbits(lo[1]);
      bfr[2] = (short)bfbits(lo[2]); bfr[3] = (short)bfbits(lo[3]);
      bfr[4] = (short)bfbits(hi[0]); bfr[5] = (short)bfbits(hi[1]);
      bfr[6] = (short)bfbits(hi[2]); bfr[7] = (short)bfbits(hi[3]);
      #pragma unroll
      for (int a = 0; a < 4; ++a)
        acc1[a][bt] = MFMA(afrag[c&1][a], bfr, acc1[a][bt]);
    }
  }

  // epilogue 1: rank-1 (k=384) + bias + relu -> bf16 -> h1f (GEMM2 B-frag order)
  #pragma unroll
  for (int a = 0; a < 4; ++a) {
    int ft = w*4 + a;
    int fb = (ft << 4) + (lh << 2);
    f32x4 bv = *(const f32x4*)(b1s + fb);
    f32x4 wv = *(const f32x4*)(w1l + fb);
    int c2  = ft >> 1;
    int lp  = l15 + ((((ft & 1) << 1) + (lane >> 5)) << 4);
    int byo = (lh & 1) << 3;
    #pragma unroll
    for (int bt = 0; bt < NBT; ++bt) {
      int bb = (bt << 4) + l15;
      float xv = x384[bb];
      float v0 = fmaxf(acc1[a][bt][0] + bv[0] + wv[0]*xv, 0.f);
      float v1 = fmaxf(acc1[a][bt][1] + bv[1] + wv[1]*xv, 0.f);
      float v2 = fmaxf(acc1[a][bt][2] + bv[2] + wv[2]*xv, 0.f);
      float v3 = fmaxf(acc1[a][bt][3] + bv[3] + wv[3]*xv, 0.f);
      unsigned plo = (unsigned)bfbits(v0) | ((unsigned)bfbits(v1) << 16);
      unsigned phi = (unsigned)bfbits(v2) | ((unsigned)bfbits(v3) << 16);
      unsigned long long pk = (unsigned long long)plo | ((unsigned long long)phi << 32);
      *(unsigned long long*)((unsigned char*)h1f + (((c2*NBT + bt)*64 + lp) << 4) + byo) = pk;
    }
  }
  __syncthreads();

  // ---------------- GEMM2: h2^T[256f x 64b] = W2^T h1^T, K = 512 ----------------
  f32x4 acc2[2][NBT];
  #pragma unroll
  for (int i = 0; i < 2; ++i)
    #pragma unroll
    for (int bt = 0; bt < NBT; ++bt) acc2[i][bt] = (f32x4)0.0f;

  #pragma unroll
  for (int c = 0; c < 16; ++c) {
    s16x8 a2[2];
    #pragma unroll
    for (int i = 0; i < 2; ++i)
      a2[i] = *(const s16x8*)(w2f + (((c*16 + (w*2 + i))*64 + lane) << 3));
    #pragma unroll
    for (int bt = 0; bt < NBT; ++bt) {
      s16x8 bfr = *(const s16x8*)(h1f + (((c*NBT + bt)*64 + lane) << 3));
      acc2[0][bt] = MFMA(a2[0], bfr, acc2[0][bt]);
      acc2[1][bt] = MFMA(a2[1], bfr, acc2[1][bt]);
    }
  }

  // epilogue 2 -> h2f
  #pragma unroll
  for (int i = 0; i < 2; ++i) {
    int ft = w*2 + i;
    int fb = (ft << 4) + (lh << 2);
    f32x4 bv = *(const f32x4*)(b2s + fb);
    int lp  = l15 + ((((ft & 1) << 1) + (lane >> 5)) << 4);
    int byo = (lh & 1) << 3;
    #pragma unroll
    for (int bt = 0; bt < NBT; ++bt) {
      float v0 = fmaxf(acc2[i][bt][0] + bv[0], 0.f);
      float v1 = fmaxf(acc2[i][bt][1] + bv[1], 0.f);
      float v2 = fmaxf(acc2[i][bt][2] + bv[2], 0.f);
      float v3 = fmaxf(acc2[i][bt][3] + bv[3], 0.f);
      unsigned plo = (unsigned)bfbits(v0) | ((unsigned)bfbits(v1) << 16);
      unsigned phi = (unsigned)bfbits(v2) | ((unsigned)bfbits(v3) << 16);
      unsigned long long pk = (unsigned long long)plo | ((unsigned long long)phi << 32);
      *(unsigned long long*)((unsigned char*)h2f + (((w*NBT + bt)*64 + lp) << 4) + byo) = pk;
    }
  }
  __syncthreads();

  // ---------------- GEMM3: h3^T[192f x 64b] = W3^T h2^T, K = 256 ----------------
  // 12 f-tiles: all waves take ft=w; waves 0..3 also take ft=8+w
  f32x4 acc3[2][NBT];
  #pragma unroll
  for (int i = 0; i < 2; ++i)
    #pragma unroll
    for (int bt = 0; bt < NBT; ++bt) acc3[i][bt] = (f32x4)0.0f;

  #pragma unroll
  for (int c = 0; c < 8; ++c) {
    s16x8 a3[2];
    a3[0] = *(const s16x8*)(w3f + (((c*12 + w)*64 + lane) << 3));
    if (w < 4) a3[1] = *(const s16x8*)(w3f + (((c*12 + 8 + w)*64 + lane) << 3));
    #pragma unroll
    for (int bt = 0; bt < NBT; ++bt) {
      s16x8 bfr = *(const s16x8*)(h2f + (((c*NBT + bt)*64 + lane) << 3));
      acc3[0][bt] = MFMA(a3[0], bfr, acc3[0][bt]);
      if (w < 4) acc3[1][bt] = MFMA(a3[1], bfr, acc3[1][bt]);
    }
  }

  // epilogue 3 -> h3p [b][196f] f32 (relu + bias)
  #pragma unroll
  for (int i = 0; i < 2; ++i) {
    if (i == 0 || w < 4) {
      int ft = (i == 0) ? w : (8 + w);
      int fb = (ft << 4) + (lh << 2);
      f32x4 bv = *(const f32x4*)(b3s + fb);
      #pragma unroll
      for (int bt = 0; bt < NBT; ++bt) {
        int bb = (bt << 4) + l15;
        f32x4 vv;
        vv[0] = fmaxf(acc3[i][bt][0] + bv[0], 0.f);
        vv[1] = fmaxf(acc3[i][bt][1] + bv[1], 0.f);
        vv[2] = fmaxf(acc3[i][bt][2] + bv[2], 0.f);
        vv[3] = fmaxf(acc3[i][bt][3] + bv[3], 0.f);
        *(f32x4*)(h3p + bb*196 + fb) = vv;
      }
    }
  }
  __syncthreads();

  // ---------------- head: out[b][j] = h3[b][:] . Wh[:, base+j] + bh[base+j] ----------------
  #pragma unroll
  for (int it = 0; it < 2; ++it) {
    int o  = it*512 + tid;
    int bb = o >> 4, j = o & 15;
    int gb = b0 + bb;
    int head = qid[gb]*2 + corr[gb];
    const unsigned short* wp = whT + (head*16 + j)*192;
    const float* hp = h3p + bb*196;
    float acc = bh[head*16 + j];
    #pragma unroll
    for (int f = 0; f < 192; f += 8) {
      s16x8 wv = *(const s16x8*)(wp + f);
      f32x4 h0 = *(const f32x4*)(hp + f);
      f32x4 h1v = *(const f32x4*)(hp + f + 4);
      acc += bf2f((unsigned short)wv[0])*h0[0] + bf2f((unsigned short)wv[1])*h0[1]
           + bf2f((unsigned short)wv[2])*h0[2] + bf2f((unsigned short)wv[3])*h0[3]
           + bf2f((unsigned short)wv[4])*h1v[0] + bf2f((unsigned short)wv[5])*h1v[1]
           + bf2f((unsigned short)wv[6])*h1v[2] + bf2f((unsigned short)wv[7])*h1v[3];
    }
    out[gb*16 + j] = acc;
  }
}

extern "C" void kernel_launch(void* const* d_in, const int* in_sizes, int n_in,
                              void* d_out, int out_size, void* d_ws, size_t ws_size,
                              hipStream_t stream) {
  (void)in_sizes; (void)n_in; (void)out_size; (void)ws_size;
  const float* x  = (const float*)d_in[0];
  const float* W1 = (const float*)d_in[1];
  const float* b1 = (const float*)d_in[2];
  const float* W2 = (const float*)d_in[3];
  const float* b2 = (const float*)d_in[4];
  const float* W3 = (const float*)d_in[5];
  const float* b3 = (const float*)d_in[6];
  const float* Wh = (const float*)d_in[7];
  const float* bh = (const float*)d_in[8];
  const int* qid  = (const int*)d_in[9];
  const int* corr = (const int*)d_in[10];
  float* out = (float*)d_out;

  unsigned short* w1f = (unsigned short*)d_ws;     // 196608 bf16
  unsigned short* w2f = w1f + 12*32*64*8;          // 131072
  unsigned short* w3f = w2f + 16*16*64*8;          // 49152
  unsigned short* whT = w3f + 8*12*64*8;           // 393216   (total ~1.5 MB)

  prep_kernel<<<3008, 256, 0, stream>>>(W1, W2, W3, Wh, w1f, w2f, w3f, whT);
  fused_mlp<<<65536 / ROWS, THREADS, 0, stream>>>(x, W1, b1, b2, b3, bh, qid, corr,
                                                  w1f, w2f, w3f, whT, out);
}

// Round 2
// 111.451 us; speedup vs baseline: 1.3839x; 1.3839x over previous
//
#include <hip/hip_runtime.h>
#include <hip/hip_bf16.h>

#define ROWS 64
#define NBT 4            // ROWS/16
#define THREADS 512

typedef __attribute__((ext_vector_type(4))) float f32x4;
typedef __attribute__((ext_vector_type(8))) short s16x8;

__device__ __forceinline__ unsigned short bfbits(float f) {
  __bf16 h = (__bf16)f;
  return __builtin_bit_cast(unsigned short, h);
}
__device__ __forceinline__ float bf2f(unsigned short h) {
  unsigned u = ((unsigned)h) << 16;
  return __builtin_bit_cast(float, u);
}

// ---------------- prep: pack weights into MFMA A-fragment order (bf16) ----------------
// Frag unit = 16B = [lane][j:8]. One thread per unit: 8 gathered reads (4 contiguous
// 64B segments per wave per j), one coalesced 16B write.
// w1f: [c:12][ft:32][lane:64][8]   (K=384 of W1; k=384 is a rank-1 term in epilogue 1)
// w2f: [c:16][ft:16][lane:64][8]
// w3f: [c: 8][ft:12][lane:64][8]
// whT: [t:2048][f:192] bf16 where t = head*16 + j
__global__ void prep_kernel(const float* __restrict__ W1, const float* __restrict__ W2,
                            const float* __restrict__ W3, const float* __restrict__ Wh,
                            unsigned short* __restrict__ w1f, unsigned short* __restrict__ w2f,
                            unsigned short* __restrict__ w3f, unsigned short* __restrict__ whT) {
  int u = blockIdx.x * blockDim.x + threadIdx.x;
  const int U1 = 24576, U2 = 16384, U3 = 6144, U4 = 49152;
  if (u < U1) {                                   // W1 frags
    int lane = u & 63, r = (u >> 6) & 31, c = u >> 11;
    int f  = r * 16 + (lane & 15);
    int kb = c * 32 + ((lane >> 4) << 3);
    s16x8 v;
    #pragma unroll
    for (int j = 0; j < 8; ++j) v[j] = (short)bfbits(W1[(kb + j) * 512 + f]);
    *(s16x8*)(w1f + (u << 3)) = v;
    return;
  }
  u -= U1;
  if (u < U2) {                                   // W2 frags
    int lane = u & 63, r = (u >> 6) & 15, c = u >> 10;
    int f  = r * 16 + (lane & 15);
    int kb = c * 32 + ((lane >> 4) << 3);
    s16x8 v;
    #pragma unroll
    for (int j = 0; j < 8; ++j) v[j] = (short)bfbits(W2[(kb + j) * 256 + f]);
    *(s16x8*)(w2f + (u << 3)) = v;
    return;
  }
  u -= U2;
  if (u < U3) {                                   // W3 frags
    int lane = u & 63, t = u >> 6;
    int c = t / 12, r = t - c * 12;
    int f  = r * 16 + (lane & 15);
    int kb = c * 32 + ((lane >> 4) << 3);
    s16x8 v;
    #pragma unroll
    for (int j = 0; j < 8; ++j) v[j] = (short)bfbits(W3[(kb + j) * 192 + f]);
    *(s16x8*)(w3f + (u << 3)) = v;
    return;
  }
  u -= U3;
  if (u < U4) {                                   // Wh transpose: [t][f]
    int fo = u >> 11, t = u & 2047;               // reads coalesced across t
    s16x8 v;
    #pragma unroll
    for (int i = 0; i < 8; ++i) v[i] = (short)bfbits(Wh[(fo * 8 + i) * 2048 + t]);
    *(s16x8*)(whT + t * 192 + fo * 8) = v;
  }
}

// ---------------- fused MLP ----------------
// LDS (78 KB -> 2 blocks/CU):
//   region A @ 0 (64 KB): h1f [c2:16][bt:4][lane:64][16B]
//       after GEMM2:  h2f @ 0 (32 KB) [c3:8][bt:4][lane:64][16B]
//                     h3b @ 32768 (26 KB) [64 rows][208 f] bf16
//   xsf @ 65536 (8 KB): 2 x [bt:4][lane:64][16B] bf16 x-fragments (double buffer)
//   b1s @ 73728 (2K) | b2s @ 75776 (1K) | b3s @ 76800 (768) | w1l @ 77568 (2K) | x384 @ 79616 (256)
#define MFMA(a, b, c) __builtin_amdgcn_mfma_f32_16x16x32_bf16((a), (b), (c), 0, 0, 0)

__launch_bounds__(THREADS, 4)
__global__ void fused_mlp(const float* __restrict__ x,
                          const float* __restrict__ W1,
                          const float* __restrict__ b1,
                          const float* __restrict__ b2,
                          const float* __restrict__ b3,
                          const float* __restrict__ bh,
                          const int* __restrict__ qid,
                          const int* __restrict__ corr,
                          const unsigned short* __restrict__ w1f,
                          const unsigned short* __restrict__ w2f,
                          const unsigned short* __restrict__ w3f,
                          const unsigned short* __restrict__ whT,
                          float* __restrict__ out) {
  __shared__ __align__(16) unsigned char lds[79872];
  unsigned short* h1f = (unsigned short*)(lds);          // GEMM2 B-frags
  unsigned short* h2f = (unsigned short*)(lds);          // GEMM3 B-frags (aliases h1f)
  unsigned short* h3b = (unsigned short*)(lds + 32768);  // [64][208] bf16
  unsigned char*  xsf = lds + 65536;                     // x frags, 2 x 4KB
  float* b1s  = (float*)(lds + 73728);
  float* b2s  = (float*)(lds + 75776);
  float* b3s  = (float*)(lds + 76800);
  float* w1l  = (float*)(lds + 77568);
  float* x384 = (float*)(lds + 79616);

  const int tid  = threadIdx.x;
  const int lane = tid & 63;
  const int w    = tid >> 6;     // wave 0..7
  const int b0   = blockIdx.x * ROWS;
  const int l15  = lane & 15;
  const int lh   = lane >> 4;    // 0..3

  // stage small constants
  b1s[tid] = b1[tid];
  w1l[tid] = W1[384 * 512 + tid];
  if (tid < 256) b2s[tid] = b2[tid];
  if (tid < 192) b3s[tid] = b3[tid];
  if (tid < 64)  x384[tid] = x[(b0 + tid) * 385 + 384];

  // x staging: thread t handles row sr = t>>3, k-quad sq = t&7 (k = 4*sq) of each chunk.
  // Fragment position: bt = sr>>4, lane' = (sr&15) + (sq>>1)*16, j0 = (sq&1)*4.
  const int sr = tid >> 3;
  const int sq = tid & 7;
  const int s_addr = ((sr >> 4) << 10) + (((sr & 15) + ((sq >> 1) << 4)) << 4) + ((sq & 1) << 3);
  const float* xrow = x + (b0 + sr) * 385 + sq * 4;

  auto stx = [&](int buf, f32x4 v) {
    unsigned u0 = (unsigned)bfbits(v[0]) | ((unsigned)bfbits(v[1]) << 16);
    unsigned u1 = (unsigned)bfbits(v[2]) | ((unsigned)bfbits(v[3]) << 16);
    unsigned long long pk = (unsigned long long)u0 | ((unsigned long long)u1 << 32);
    *(unsigned long long*)(xsf + buf * 4096 + s_addr) = pk;
  };

  // ---------------- GEMM1: h1^T[512f x 64b] = W1^T x^T, K=384 (+rank-1 k=384) ----------------
  f32x4 acc1[4][NBT];
  #pragma unroll
  for (int a = 0; a < 4; ++a)
    #pragma unroll
    for (int bt = 0; bt < NBT; ++bt) acc1[a][bt] = (f32x4)0.0f;

  stx(0, *(const f32x4*)(xrow));   // stage chunk 0

  #pragma unroll
  for (int c = 0; c < 12; ++c) {
    // issue global loads for this iteration's A-frags and next chunk's x BEFORE the barrier
    s16x8 af[4];
    #pragma unroll
    for (int a = 0; a < 4; ++a)
      af[a] = *(const s16x8*)(w1f + (((c * 32 + (w * 4 + a)) * 64 + lane) << 3));
    f32x4 pv;
    if (c + 1 < 12) pv = *(const f32x4*)(xrow + (c + 1) * 32);
    __syncthreads();   // chunk c frags visible; all reads of buffer (c+1)&1 (chunk c-1) done
    const unsigned short* xb = (const unsigned short*)(xsf + (c & 1) * 4096);
    #pragma unroll
    for (int bt = 0; bt < NBT; ++bt) {
      s16x8 bfr = *(const s16x8*)(xb + ((bt * 64 + lane) << 3));
      #pragma unroll
      for (int a = 0; a < 4; ++a)
        acc1[a][bt] = MFMA(af[a], bfr, acc1[a][bt]);
    }
    if (c + 1 < 12) stx((c + 1) & 1, pv);
  }

  // epilogue 1: rank-1 (k=384) + bias + relu -> bf16 -> h1f (GEMM2 B-frag order)
  #pragma unroll
  for (int a = 0; a < 4; ++a) {
    int ft = w * 4 + a;
    int fb = (ft << 4) + (lh << 2);
    f32x4 bv = *(const f32x4*)(b1s + fb);
    f32x4 wv = *(const f32x4*)(w1l + fb);
    int c2  = ft >> 1;
    int lp  = l15 + ((((ft & 1) << 1) + (lh >> 1)) << 4);
    int byo = (lh & 1) << 3;
    #pragma unroll
    for (int bt = 0; bt < NBT; ++bt) {
      int bb = (bt << 4) + l15;
      float xv = x384[bb];
      float v0 = fmaxf(acc1[a][bt][0] + bv[0] + wv[0] * xv, 0.f);
      float v1 = fmaxf(acc1[a][bt][1] + bv[1] + wv[1] * xv, 0.f);
      float v2 = fmaxf(acc1[a][bt][2] + bv[2] + wv[2] * xv, 0.f);
      float v3 = fmaxf(acc1[a][bt][3] + bv[3] + wv[3] * xv, 0.f);
      unsigned plo = (unsigned)bfbits(v0) | ((unsigned)bfbits(v1) << 16);
      unsigned phi = (unsigned)bfbits(v2) | ((unsigned)bfbits(v3) << 16);
      unsigned long long pk = (unsigned long long)plo | ((unsigned long long)phi << 32);
      *(unsigned long long*)((unsigned char*)h1f + (((c2 * NBT + bt) * 64 + lp) << 4) + byo) = pk;
    }
  }
  __syncthreads();

  // ---------------- GEMM2: h2^T[256f x 64b] = W2^T h1^T, K=512 ----------------
  f32x4 acc2[2][NBT];
  #pragma unroll
  for (int i = 0; i < 2; ++i)
    #pragma unroll
    for (int bt = 0; bt < NBT; ++bt) acc2[i][bt] = (f32x4)0.0f;

  #pragma unroll
  for (int c = 0; c < 16; ++c) {
    s16x8 a2[2];
    #pragma unroll
    for (int i = 0; i < 2; ++i)
      a2[i] = *(const s16x8*)(w2f + (((c * 16 + (w * 2 + i)) * 64 + lane) << 3));
    #pragma unroll
    for (int bt = 0; bt < NBT; ++bt) {
      s16x8 bfr = *(const s16x8*)(h1f + (((c * NBT + bt) * 64 + lane) << 3));
      acc2[0][bt] = MFMA(a2[0], bfr, acc2[0][bt]);
      acc2[1][bt] = MFMA(a2[1], bfr, acc2[1][bt]);
    }
  }
  __syncthreads();   // all h1f reads done before h2f writes (same LDS region)

  // epilogue 2 -> h2f (GEMM3 B-frag order)
  #pragma unroll
  for (int i = 0; i < 2; ++i) {
    int ft = w * 2 + i;
    int fb = (ft << 4) + (lh << 2);
    f32x4 bv = *(const f32x4*)(b2s + fb);
    int c3  = ft >> 1;
    int lp  = l15 + ((((ft & 1) << 1) + (lh >> 1)) << 4);
    int byo = (lh & 1) << 3;
    #pragma unroll
    for (int bt = 0; bt < NBT; ++bt) {
      float v0 = fmaxf(acc2[i][bt][0] + bv[0], 0.f);
      float v1 = fmaxf(acc2[i][bt][1] + bv[1], 0.f);
      float v2 = fmaxf(acc2[i][bt][2] + bv[2], 0.f);
      float v3 = fmaxf(acc2[i][bt][3] + bv[3], 0.f);
      unsigned plo = (unsigned)bfbits(v0) | ((unsigned)bfbits(v1) << 16);
      unsigned phi = (unsigned)bfbits(v2) | ((unsigned)bfbits(v3) << 16);
      unsigned long long pk = (unsigned long long)plo | ((unsigned long long)phi << 32);
      *(unsigned long long*)((unsigned char*)h2f + (((c3 * NBT + bt) * 64 + lp) << 4) + byo) = pk;
    }
  }
  __syncthreads();

  // ---------------- GEMM3: h3^T[192f x 64b] = W3^T h2^T, K=256 ----------------
  f32x4 acc3[2][NBT];
  #pragma unroll
  for (int i = 0; i < 2; ++i)
    #pragma unroll
    for (int bt = 0; bt < NBT; ++bt) acc3[i][bt] = (f32x4)0.0f;

  #pragma unroll
  for (int c = 0; c < 8; ++c) {
    s16x8 a3[2];
    a3[0] = *(const s16x8*)(w3f + (((c * 12 + w) * 64 + lane) << 3));
    if (w < 4) a3[1] = *(const s16x8*)(w3f + (((c * 12 + 8 + w) * 64 + lane) << 3));
    #pragma unroll
    for (int bt = 0; bt < NBT; ++bt) {
      s16x8 bfr = *(const s16x8*)(h2f + (((c * NBT + bt) * 64 + lane) << 3));
      acc3[0][bt] = MFMA(a3[0], bfr, acc3[0][bt]);
      if (w < 4) acc3[1][bt] = MFMA(a3[1], bfr, acc3[1][bt]);
    }
  }

  // epilogue 3 -> h3b [64][208] bf16 (bias + relu); disjoint from h2f region, no barrier needed
  #pragma unroll
  for (int i = 0; i < 2; ++i) {
    if (i == 0 || w < 4) {
      int ft = (i == 0) ? w : (8 + w);
      int fb = (ft << 4) + (lh << 2);
      f32x4 bv = *(const f32x4*)(b3s + fb);
      #pragma unroll
      for (int bt = 0; bt < NBT; ++bt) {
        int bb = (bt << 4) + l15;
        float v0 = fmaxf(acc3[i][bt][0] + bv[0], 0.f);
        float v1 = fmaxf(acc3[i][bt][1] + bv[1], 0.f);
        float v2 = fmaxf(acc3[i][bt][2] + bv[2], 0.f);
        float v3 = fmaxf(acc3[i][bt][3] + bv[3], 0.f);
        unsigned plo = (unsigned)bfbits(v0) | ((unsigned)bfbits(v1) << 16);
        unsigned phi = (unsigned)bfbits(v2) | ((unsigned)bfbits(v3) << 16);
        unsigned long long pk = (unsigned long long)plo | ((unsigned long long)phi << 32);
        *(unsigned long long*)((unsigned char*)h3b + bb * 416 + (ft << 5) + (lh << 3)) = pk;
      }
    }
  }
  __syncthreads();

  // ---------------- head: out[b][j] = h3[b][:] . Wh[:, head*16+j] + bh[head*16+j] ----------------
  #pragma unroll
  for (int it = 0; it < 2; ++it) {
    int o  = it * 512 + tid;
    int bb = o >> 4, j = o & 15;
    int gb = b0 + bb;
    int t  = qid[gb] * 32 + corr[gb] * 16 + j;
    const unsigned short* wp = whT + t * 192;
    const unsigned short* hp = h3b + bb * 208;
    float acc = bh[t];
    #pragma unroll 4
    for (int f = 0; f < 192; f += 8) {
      s16x8 wv = *(const s16x8*)(wp + f);
      s16x8 hv = *(const s16x8*)(hp + f);
      #pragma unroll
      for (int e = 0; e < 8; ++e)
        acc += bf2f((unsigned short)wv[e]) * bf2f((unsigned short)hv[e]);
    }
    out[gb * 16 + j] = acc;
  }
}

extern "C" void kernel_launch(void* const* d_in, const int* in_sizes, int n_in,
                              void* d_out, int out_size, void* d_ws, size_t ws_size,
                              hipStream_t stream) {
  (void)in_sizes; (void)n_in; (void)out_size; (void)ws_size;
  const float* x  = (const float*)d_in[0];
  const float* W1 = (const float*)d_in[1];
  const float* b1 = (const float*)d_in[2];
  const float* W2 = (const float*)d_in[3];
  const float* b2 = (const float*)d_in[4];
  const float* W3 = (const float*)d_in[5];
  const float* b3 = (const float*)d_in[6];
  const float* Wh = (const float*)d_in[7];
  const float* bh = (const float*)d_in[8];
  const int* qid  = (const int*)d_in[9];
  const int* corr = (const int*)d_in[10];
  float* out = (float*)d_out;

  unsigned short* w1f = (unsigned short*)d_ws;     // 196608 bf16
  unsigned short* w2f = w1f + 12 * 32 * 64 * 8;    // 131072
  unsigned short* w3f = w2f + 16 * 16 * 64 * 8;    // 49152
  unsigned short* whT = w3f + 8 * 12 * 64 * 8;     // 393216   (total ~1.5 MB)

  prep_kernel<<<376, 256, 0, stream>>>(W1, W2, W3, Wh, w1f, w2f, w3f, whT);
  fused_mlp<<<65536 / ROWS, THREADS, 0, stream>>>(x, W1, b1, b2, b3, bh, qid, corr,
                                                  w1f, w2f, w3f, whT, out);
}

// Round 3
// 85.026 us; speedup vs baseline: 1.8140x; 1.3108x over previous
//
#include <hip/hip_runtime.h>
#include <hip/hip_bf16.h>

#define THREADS 1024
#define ROWS 64

typedef __attribute__((ext_vector_type(4))) float f32x4;
typedef __attribute__((ext_vector_type(8))) short s16x8;

__device__ __forceinline__ unsigned short bfbits(float f) {
  __bf16 h = (__bf16)f;
  return __builtin_bit_cast(unsigned short, h);
}
__device__ __forceinline__ float bf2f(unsigned short h) {
  unsigned u = ((unsigned)h) << 16;
  return __builtin_bit_cast(float, u);
}

// ---------------- prep: pack weights into MFMA A-fragment order (bf16) ----------------
// A-frag for mfma_f32_16x16x32_bf16: lane l holds A[m=l&15][k=(l>>4)*8+j], j=0..7
// w1f: [c:12][ft:32][lane:64][8]   (K=384 of W1; k=384 is a rank-1 term in epilogue 1)
// w2f: [c:16][ft:16][lane:64][8]
// w3f: [c: 8][ft:12][lane:64][8]
// whTj: [head:128][fo:24][j:16][8] bf16  (head gathers 256B-contiguous per 16-lane group)
__global__ void prep_kernel(const float* __restrict__ W1, const float* __restrict__ W2,
                            const float* __restrict__ W3, const float* __restrict__ Wh,
                            unsigned short* __restrict__ w1f, unsigned short* __restrict__ w2f,
                            unsigned short* __restrict__ w3f, unsigned short* __restrict__ whT) {
  int u = blockIdx.x * blockDim.x + threadIdx.x;
  const int U1 = 24576, U2 = 16384, U3 = 6144, U4 = 49152;
  if (u < U1) {                                   // W1 frags
    int lane = u & 63, r = (u >> 6) & 31, c = u >> 11;
    int f  = r * 16 + (lane & 15);
    int kb = c * 32 + ((lane >> 4) << 3);
    s16x8 v;
    #pragma unroll
    for (int j = 0; j < 8; ++j) v[j] = (short)bfbits(W1[(kb + j) * 512 + f]);
    *(s16x8*)(w1f + (u << 3)) = v;
    return;
  }
  u -= U1;
  if (u < U2) {                                   // W2 frags
    int lane = u & 63, r = (u >> 6) & 15, c = u >> 10;
    int f  = r * 16 + (lane & 15);
    int kb = c * 32 + ((lane >> 4) << 3);
    s16x8 v;
    #pragma unroll
    for (int j = 0; j < 8; ++j) v[j] = (short)bfbits(W2[(kb + j) * 256 + f]);
    *(s16x8*)(w2f + (u << 3)) = v;
    return;
  }
  u -= U2;
  if (u < U3) {                                   // W3 frags
    int lane = u & 63, t = u >> 6;
    int c = t / 12, r = t - c * 12;
    int f  = r * 16 + (lane & 15);
    int kb = c * 32 + ((lane >> 4) << 3);
    s16x8 v;
    #pragma unroll
    for (int j = 0; j < 8; ++j) v[j] = (short)bfbits(W3[(kb + j) * 192 + f]);
    *(s16x8*)(w3f + (u << 3)) = v;
    return;
  }
  u -= U3;
  if (u < U4) {                                   // Wh -> [head][fo][j][8]
    int j = u & 15, v2 = u >> 4;
    int fo = v2 % 24, head = v2 / 24;
    s16x8 v;
    #pragma unroll
    for (int i = 0; i < 8; ++i) v[i] = (short)bfbits(Wh[(fo * 8 + i) * 2048 + head * 16 + j]);
    *(s16x8*)(whT + u * 8) = v;
  }
}

// ---------------- fused MLP: 1024 threads (16 waves), 1 block/CU, barrier-free GEMMs ----------------
// LDS (120832 B):
//   xall @ 0      : 49152  (12 chunks x [bt:4][lane':64][16B] bf16 frags, khalf-XOR swizzled)
//   h1f  @ 49152  : 65536  (GEMM2 B-frags, swizzled)      | h3p aliases (f32 [64][204])
//   h2f  @ 0      : 32768  (GEMM3 B-frags, aliases xall)
//   b1s @114688 | b2s @116736 | b3s @117760 | w1l @118528 | x384 @120576
#define MFMA(a, b, c) __builtin_amdgcn_mfma_f32_16x16x32_bf16((a), (b), (c), 0, 0, 0)
#define SWZ(lane) (((lane) * 16) ^ ((((lane) >> 4) & 3) << 5))

__global__ __launch_bounds__(THREADS, 4)
void fused_mlp(const float* __restrict__ x,
               const float* __restrict__ b1,
               const float* __restrict__ b2,
               const float* __restrict__ b3,
               const float* __restrict__ bh,
               const float* __restrict__ W1,
               const int* __restrict__ qid,
               const int* __restrict__ corr,
               const unsigned short* __restrict__ w1f,
               const unsigned short* __restrict__ w2f,
               const unsigned short* __restrict__ w3f,
               const unsigned short* __restrict__ whT,
               float* __restrict__ out) {
  __shared__ __align__(16) unsigned char lds[120832];
  unsigned char* xall = lds;                              // GEMM1 B-frags
  unsigned char* h1f  = lds + 49152;                      // GEMM2 B-frags
  unsigned char* h2f  = lds;                              // GEMM3 B-frags (alias xall)
  float* h3p          = (float*)(lds + 49152);            // [64][204] f32 (alias h1f)
  float* b1s  = (float*)(lds + 114688);
  float* b2s  = (float*)(lds + 116736);
  float* b3s  = (float*)(lds + 117760);
  float* w1l  = (float*)(lds + 118528);
  float* x384 = (float*)(lds + 120576);

  const int tid  = threadIdx.x;
  const int lane = tid & 63;
  const int w    = tid >> 6;     // wave 0..15
  const int b0   = blockIdx.x * ROWS;
  const int l15  = lane & 15;
  const int lh   = lane >> 4;    // 0..3

  // ---- x stage mapping: thread -> one 16B frag per phase (4 chunks/phase) ----
  const int s_kh = tid & 3;               // khalf (8 k each)
  const int s_sr = (tid >> 2) & 63;       // row
  const int s_cl = tid >> 8;              // chunk-within-phase 0..3
  const int s_off = ((s_sr >> 4) << 10) + SWZ((s_sr & 15) + (s_kh << 4));
  const float* s_x = x + (size_t)(b0 + s_sr) * 385 + (s_kh << 3);

  f32x4 lo, hi;
  auto sload = [&](int p) {
    int c = (p << 2) + s_cl;
    lo = *(const f32x4*)(s_x + c * 32);
    hi = *(const f32x4*)(s_x + c * 32 + 4);
  };
  auto swrite = [&](int p) {
    int c = (p << 2) + s_cl;
    s16x8 v;
    v[0] = (short)bfbits(lo[0]); v[1] = (short)bfbits(lo[1]);
    v[2] = (short)bfbits(lo[2]); v[3] = (short)bfbits(lo[3]);
    v[4] = (short)bfbits(hi[0]); v[5] = (short)bfbits(hi[1]);
    v[6] = (short)bfbits(hi[2]); v[7] = (short)bfbits(hi[3]);
    *(s16x8*)(xall + (c << 12) + s_off) = v;
  };

  // ---- phase A: stage chunks 0-3 + smalls ----
  sload(0);
  if (tid < 512)                    { b1s[tid] = b1[tid]; w1l[tid] = W1[384 * 512 + tid]; }
  else if (tid < 768)               { b2s[tid - 512] = b2[tid - 512]; }
  else if (tid < 960)               { b3s[tid - 768] = b3[tid - 768]; }
  else                              { x384[tid - 960] = x[(size_t)(b0 + tid - 960) * 385 + 384]; }
  swrite(0);
  __syncthreads();

  // ---------------- GEMM1: h1^T[512f x 64b] = W1^T x^T, K=384 ----------------
  f32x4 acc1[2][4];
  #pragma unroll
  for (int a = 0; a < 2; ++a)
    #pragma unroll
    for (int bt = 0; bt < 4; ++bt) acc1[a][bt] = (f32x4)0.0f;

  const int swz_l = SWZ(lane);

#define G1_CHUNKS(C0, C1)                                                              \
  _Pragma("unroll")                                                                    \
  for (int c = C0; c < C1; ++c) {                                                      \
    s16x8 a0 = *(const s16x8*)(w1f + (((c * 32 + w * 2 + 0) * 64 + lane) << 3));       \
    s16x8 a1 = *(const s16x8*)(w1f + (((c * 32 + w * 2 + 1) * 64 + lane) << 3));       \
    _Pragma("unroll")                                                                  \
    for (int bt = 0; bt < 4; ++bt) {                                                   \
      s16x8 bfr = *(const s16x8*)(xall + (c << 12) + (bt << 10) + swz_l);              \
      acc1[0][bt] = MFMA(a0, bfr, acc1[0][bt]);                                        \
      acc1[1][bt] = MFMA(a1, bfr, acc1[1][bt]);                                        \
    }                                                                                  \
  }

  sload(1);
  G1_CHUNKS(0, 4)
  swrite(1);
  __syncthreads();

  sload(2);
  G1_CHUNKS(4, 8)
  swrite(2);
  __syncthreads();

  G1_CHUNKS(8, 12)

  // epilogue 1: rank-1 (k=384) + bias + relu -> bf16 frags -> h1f
  #pragma unroll
  for (int a = 0; a < 2; ++a) {
    int ft = w * 2 + a;
    int fb = (ft << 4) + (lh << 2);
    f32x4 bv = *(const f32x4*)(b1s + fb);
    f32x4 wv = *(const f32x4*)(w1l + fb);
    int kh = ((a << 1) + (lh >> 1)) & 3;
    int so = SWZ(l15 + (kh << 4)) + ((lh & 1) << 3);
    #pragma unroll
    for (int bt = 0; bt < 4; ++bt) {
      float xv = x384[(bt << 4) + l15];
      float v0 = fmaxf(acc1[a][bt][0] + bv[0] + wv[0] * xv, 0.f);
      float v1 = fmaxf(acc1[a][bt][1] + bv[1] + wv[1] * xv, 0.f);
      float v2 = fmaxf(acc1[a][bt][2] + bv[2] + wv[2] * xv, 0.f);
      float v3 = fmaxf(acc1[a][bt][3] + bv[3] + wv[3] * xv, 0.f);
      unsigned plo = (unsigned)bfbits(v0) | ((unsigned)bfbits(v1) << 16);
      unsigned phi = (unsigned)bfbits(v2) | ((unsigned)bfbits(v3) << 16);
      unsigned long long pk = (unsigned long long)plo | ((unsigned long long)phi << 32);
      *(unsigned long long*)(h1f + (((w << 2) + bt) << 10) + so) = pk;
    }
  }
  __syncthreads();

  // ---------------- GEMM2: h2^T[256f x 64b] = W2^T h1^T, K=512 (barrier-free) ----------------
  f32x4 acc2[4];
  #pragma unroll
  for (int bt = 0; bt < 4; ++bt) acc2[bt] = (f32x4)0.0f;

  #pragma unroll
  for (int c = 0; c < 16; ++c) {
    s16x8 a2 = *(const s16x8*)(w2f + (((c * 16 + w) * 64 + lane) << 3));
    #pragma unroll
    for (int bt = 0; bt < 4; ++bt) {
      s16x8 bfr = *(const s16x8*)(h1f + ((c << 12) + (bt << 10)) + swz_l);
      acc2[bt] = MFMA(a2, bfr, acc2[bt]);
    }
  }

  // epilogue 2 -> h2f (GEMM3 B-frags; region = xall, dead since GEMM1)
  {
    int fb = (w << 4) + (lh << 2);
    f32x4 bv = *(const f32x4*)(b2s + fb);
    int kh = (((w & 1) << 1) + (lh >> 1)) & 3;
    int so = SWZ(l15 + (kh << 4)) + ((lh & 1) << 3);
    #pragma unroll
    for (int bt = 0; bt < 4; ++bt) {
      float v0 = fmaxf(acc2[bt][0] + bv[0], 0.f);
      float v1 = fmaxf(acc2[bt][1] + bv[1], 0.f);
      float v2 = fmaxf(acc2[bt][2] + bv[2], 0.f);
      float v3 = fmaxf(acc2[bt][3] + bv[3], 0.f);
      unsigned plo = (unsigned)bfbits(v0) | ((unsigned)bfbits(v1) << 16);
      unsigned phi = (unsigned)bfbits(v2) | ((unsigned)bfbits(v3) << 16);
      unsigned long long pk = (unsigned long long)plo | ((unsigned long long)phi << 32);
      *(unsigned long long*)(h2f + ((((w >> 1) << 2) + bt) << 10) + so) = pk;
    }
  }
  __syncthreads();

  // ---------------- GEMM3: h3^T[192f x 64b] = W3^T h2^T, K=256 (waves 0..11) ----------------
  if (w < 12) {
    f32x4 acc3[4];
    #pragma unroll
    for (int bt = 0; bt < 4; ++bt) acc3[bt] = (f32x4)0.0f;

    #pragma unroll
    for (int c = 0; c < 8; ++c) {
      s16x8 a3 = *(const s16x8*)(w3f + (((c * 12 + w) * 64 + lane) << 3));
      #pragma unroll
      for (int bt = 0; bt < 4; ++bt) {
        s16x8 bfr = *(const s16x8*)(h2f + ((c << 12) + (bt << 10)) + swz_l);
        acc3[bt] = MFMA(a3, bfr, acc3[bt]);
      }
    }

    // epilogue 3 -> h3p [64][204] f32 (bias + relu); region = h1f, reads done pre-barrier
    int fb = (w << 4) + (lh << 2);
    f32x4 bv = *(const f32x4*)(b3s + fb);
    #pragma unroll
    for (int bt = 0; bt < 4; ++bt) {
      int bb = (bt << 4) + l15;
      f32x4 vv;
      vv[0] = fmaxf(acc3[bt][0] + bv[0], 0.f);
      vv[1] = fmaxf(acc3[bt][1] + bv[1], 0.f);
      vv[2] = fmaxf(acc3[bt][2] + bv[2], 0.f);
      vv[3] = fmaxf(acc3[bt][3] + bv[3], 0.f);
      *(f32x4*)(h3p + bb * 204 + fb) = vv;
    }
  }
  __syncthreads();

  // ---------------- head: out[b][j] = h3[b][:] . Wh[:, head*16+j] + bh[head*16+j] ----------------
  {
    int bb = tid >> 4, j = tid & 15;
    int gb = b0 + bb;
    int head = qid[gb] * 2 + corr[gb];
    const unsigned short* wp = whT + ((head * 24) * 16 + j) * 8;
    const float* hp = h3p + bb * 204;
    float acc = bh[(head << 4) + j];
    #pragma unroll 6
    for (int fo = 0; fo < 24; ++fo) {
      s16x8 wv = *(const s16x8*)(wp + fo * 128);
      f32x4 h0 = *(const f32x4*)(hp + fo * 8);
      f32x4 h1v = *(const f32x4*)(hp + fo * 8 + 4);
      acc += bf2f((unsigned short)wv[0]) * h0[0] + bf2f((unsigned short)wv[1]) * h0[1]
           + bf2f((unsigned short)wv[2]) * h0[2] + bf2f((unsigned short)wv[3]) * h0[3]
           + bf2f((unsigned short)wv[4]) * h1v[0] + bf2f((unsigned short)wv[5]) * h1v[1]
           + bf2f((unsigned short)wv[6]) * h1v[2] + bf2f((unsigned short)wv[7]) * h1v[3];
    }
    out[(size_t)gb * 16 + j] = acc;
  }
}

extern "C" void kernel_launch(void* const* d_in, const int* in_sizes, int n_in,
                              void* d_out, int out_size, void* d_ws, size_t ws_size,
                              hipStream_t stream) {
  (void)in_sizes; (void)n_in; (void)out_size; (void)ws_size;
  const float* x  = (const float*)d_in[0];
  const float* W1 = (const float*)d_in[1];
  const float* b1 = (const float*)d_in[2];
  const float* W2 = (const float*)d_in[3];
  const float* b2 = (const float*)d_in[4];
  const float* W3 = (const float*)d_in[5];
  const float* b3 = (const float*)d_in[6];
  const float* Wh = (const float*)d_in[7];
  const float* bh = (const float*)d_in[8];
  const int* qid  = (const int*)d_in[9];
  const int* corr = (const int*)d_in[10];
  float* out = (float*)d_out;

  unsigned short* w1f = (unsigned short*)d_ws;     // 196608 bf16
  unsigned short* w2f = w1f + 12 * 32 * 64 * 8;    // 131072
  unsigned short* w3f = w2f + 16 * 16 * 64 * 8;    // 49152
  unsigned short* whT = w3f + 8 * 12 * 64 * 8;     // 393216   (total ~1.54 MB)

  prep_kernel<<<376, 256, 0, stream>>>(W1, W2, W3, Wh, w1f, w2f, w3f, whT);
  fused_mlp<<<65536 / ROWS, THREADS, 0, stream>>>(x, b1, b2, b3, bh, W1, qid, corr,
                                                  w1f, w2f, w3f, whT, out);
}